// Round 1
// baseline (768.627 us; speedup 1.0000x reference)
//
#include <hip/hip_runtime.h>
#include <math.h>

// Problem constants
// B=8, INCH=64, MIDCH=32, H=W=128, downscale 2 -> h=w=64, N=4096

// ---------------------------------------------------------------------------
// Kernel 1: fused 2x2 avg-pool + three 1x1-conv projections
// theta[b][n][32] (from cross), g[b][n][32] (from primary), phi[b][32][n] (from primary)
// ---------------------------------------------------------------------------
__global__ __launch_bounds__(256) void pool_project_kernel(
    const float* __restrict__ primary, const float* __restrict__ cross,
    const float* __restrict__ w_theta, const float* __restrict__ w_phi,
    const float* __restrict__ w_g,
    float* __restrict__ theta, float* __restrict__ phi, float* __restrict__ g)
{
    int gid = blockIdx.x * 256 + threadIdx.x;   // b*4096 + n, total 32768
    int b = gid >> 12;
    int n = gid & 4095;
    int yy = n >> 6, xx = n & 63;

    size_t base0 = (size_t)b * 64 * 16384 + (size_t)(2 * yy) * 128 + 2 * xx;
    const float* pbase = primary + base0;
    const float* cbase = cross + base0;

    float th[32], ph[32], gg[32];
#pragma unroll
    for (int m = 0; m < 32; ++m) { th[m] = 0.f; ph[m] = 0.f; gg[m] = 0.f; }

    for (int c = 0; c < 64; ++c) {
        float2 p0 = *(const float2*)(pbase + (size_t)c * 16384);
        float2 p1 = *(const float2*)(pbase + (size_t)c * 16384 + 128);
        float2 c0 = *(const float2*)(cbase + (size_t)c * 16384);
        float2 c1 = *(const float2*)(cbase + (size_t)c * 16384 + 128);
        float pdc = 0.25f * ((p0.x + p0.y) + (p1.x + p1.y));
        float cdc = 0.25f * ((c0.x + c0.y) + (c1.x + c1.y));
#pragma unroll
        for (int m = 0; m < 32; ++m) {
            th[m] = fmaf(w_theta[m * 64 + c], cdc, th[m]);
            ph[m] = fmaf(w_phi[m * 64 + c], pdc, ph[m]);
            gg[m] = fmaf(w_g[m * 64 + c], pdc, gg[m]);
        }
    }

    float* tp = theta + (size_t)gid * 32;
    float* gp = g + (size_t)gid * 32;
#pragma unroll
    for (int m = 0; m < 32; m += 4) {
        *(float4*)(tp + m) = make_float4(th[m], th[m+1], th[m+2], th[m+3]);
        *(float4*)(gp + m) = make_float4(gg[m], gg[m+1], gg[m+2], gg[m+3]);
    }
    float* pp = phi + (size_t)b * 32 * 4096 + n;
#pragma unroll
    for (int m = 0; m < 32; ++m) pp[(size_t)m * 4096] = ph[m];
}

// ---------------------------------------------------------------------------
// Kernel 2: flash attention, f32.  Per block: one batch, 64 queries.
// S[q][k] = sum_c theta[q][c]*phi[c][k]; online softmax; y[b][m][q] = sum_k P*g[k][m]
// ---------------------------------------------------------------------------
__global__ __launch_bounds__(256) void attn_kernel(
    const float* __restrict__ theta, const float* __restrict__ phi,
    const float* __restrict__ g, float* __restrict__ y)
{
    __shared__ float thT[32][64];   // [c][q]
    __shared__ float phiT[32][64];  // [c][k]
    __shared__ float gT[64][32];    // [k][m]
    __shared__ float pT[64][64];    // [q][k]

    int b = blockIdx.y, qt = blockIdx.x;
    int t = threadIdx.x;

    const float* thsrc = theta + ((size_t)b * 4096 + (size_t)qt * 64) * 32;
#pragma unroll
    for (int i = 0; i < 8; ++i) {
        int flat = i * 256 + t;
        int c = flat >> 6, q = flat & 63;
        thT[c][q] = thsrc[q * 32 + c];
    }

    int qg = t >> 4, kg = t & 15;
    int q0 = qg * 4, m0 = kg * 2;

    float m_r[4], l_r[4], acc[4][2];
#pragma unroll
    for (int i = 0; i < 4; ++i) {
        m_r[i] = -1e30f; l_r[i] = 0.f; acc[i][0] = 0.f; acc[i][1] = 0.f;
    }

    const float* phisrc = phi + (size_t)b * 32 * 4096;
    const float* gsrc   = g   + (size_t)b * 4096 * 32;

    for (int kt = 0; kt < 64; ++kt) {
        __syncthreads();   // previous iteration's PV done before overwriting tiles
#pragma unroll
        for (int i = 0; i < 8; ++i) {
            int flat = i * 256 + t;
            int c = flat >> 6, k = flat & 63;
            phiT[c][k] = phisrc[(size_t)c * 4096 + kt * 64 + k];
        }
#pragma unroll
        for (int i = 0; i < 8; ++i) {
            int flat = i * 256 + t;
            int k = flat >> 5, mm = flat & 31;
            gT[k][mm] = gsrc[(size_t)(kt * 64 + k) * 32 + mm];
        }
        __syncthreads();

        // ---- scores: 4x4 register tile ----
        float s[4][4];
#pragma unroll
        for (int i = 0; i < 4; ++i)
#pragma unroll
            for (int j = 0; j < 4; ++j) s[i][j] = 0.f;

        for (int c = 0; c < 32; ++c) {
            float4 tv = *(const float4*)&thT[c][q0];
            float4 pv = *(const float4*)&phiT[c][kg * 4];
            s[0][0]=fmaf(tv.x,pv.x,s[0][0]); s[0][1]=fmaf(tv.x,pv.y,s[0][1]);
            s[0][2]=fmaf(tv.x,pv.z,s[0][2]); s[0][3]=fmaf(tv.x,pv.w,s[0][3]);
            s[1][0]=fmaf(tv.y,pv.x,s[1][0]); s[1][1]=fmaf(tv.y,pv.y,s[1][1]);
            s[1][2]=fmaf(tv.y,pv.z,s[1][2]); s[1][3]=fmaf(tv.y,pv.w,s[1][3]);
            s[2][0]=fmaf(tv.z,pv.x,s[2][0]); s[2][1]=fmaf(tv.z,pv.y,s[2][1]);
            s[2][2]=fmaf(tv.z,pv.z,s[2][2]); s[2][3]=fmaf(tv.z,pv.w,s[2][3]);
            s[3][0]=fmaf(tv.w,pv.x,s[3][0]); s[3][1]=fmaf(tv.w,pv.y,s[3][1]);
            s[3][2]=fmaf(tv.w,pv.z,s[3][2]); s[3][3]=fmaf(tv.w,pv.w,s[3][3]);
        }

        // ---- online softmax update (per q-row, reduced across the 16 kg lanes) ----
#pragma unroll
        for (int i = 0; i < 4; ++i) {
            float tm = fmaxf(fmaxf(s[i][0], s[i][1]), fmaxf(s[i][2], s[i][3]));
            tm = fmaxf(tm, __shfl_xor(tm, 1));
            tm = fmaxf(tm, __shfl_xor(tm, 2));
            tm = fmaxf(tm, __shfl_xor(tm, 4));
            tm = fmaxf(tm, __shfl_xor(tm, 8));
            float nm = fmaxf(m_r[i], tm);
            float scl = __expf(m_r[i] - nm);
            float p0_ = __expf(s[i][0] - nm);
            float p1_ = __expf(s[i][1] - nm);
            float p2_ = __expf(s[i][2] - nm);
            float p3_ = __expf(s[i][3] - nm);
            *(float4*)&pT[q0 + i][kg * 4] = make_float4(p0_, p1_, p2_, p3_);
            float ps = (p0_ + p1_) + (p2_ + p3_);
            ps += __shfl_xor(ps, 1);
            ps += __shfl_xor(ps, 2);
            ps += __shfl_xor(ps, 4);
            ps += __shfl_xor(ps, 8);
            l_r[i] = l_r[i] * scl + ps;
            m_r[i] = nm;
            acc[i][0] *= scl;
            acc[i][1] *= scl;
        }

        // ---- PV: pT rows q0..q0+3 written entirely by this wave (in-order LDS) ----
        for (int k4 = 0; k4 < 64; k4 += 4) {
            float4 pq[4];
#pragma unroll
            for (int i = 0; i < 4; ++i) pq[i] = *(const float4*)&pT[q0 + i][k4];
            float2 gv[4];
#pragma unroll
            for (int j = 0; j < 4; ++j) gv[j] = *(const float2*)&gT[k4 + j][m0];
#pragma unroll
            for (int i = 0; i < 4; ++i) {
                acc[i][0] = fmaf(pq[i].x, gv[0].x, acc[i][0]);
                acc[i][0] = fmaf(pq[i].y, gv[1].x, acc[i][0]);
                acc[i][0] = fmaf(pq[i].z, gv[2].x, acc[i][0]);
                acc[i][0] = fmaf(pq[i].w, gv[3].x, acc[i][0]);
                acc[i][1] = fmaf(pq[i].x, gv[0].y, acc[i][1]);
                acc[i][1] = fmaf(pq[i].y, gv[1].y, acc[i][1]);
                acc[i][1] = fmaf(pq[i].z, gv[2].y, acc[i][1]);
                acc[i][1] = fmaf(pq[i].w, gv[3].y, acc[i][1]);
            }
        }
    }

    // epilogue: y[b][m][qt*64 + q]
    float* ybase = y + (size_t)b * 32 * 4096 + qt * 64;
#pragma unroll
    for (int i = 0; i < 4; ++i) {
        float inv = 1.0f / l_r[i];
        ybase[(size_t)m0 * 4096 + q0 + i]       = acc[i][0] * inv;
        ybase[(size_t)(m0 + 1) * 4096 + q0 + i] = acc[i][1] * inv;
    }
}

// ---------------------------------------------------------------------------
// Kernel 3: bilinear upsample x2, align_corners=True  (64x64 -> 128x128)
// ---------------------------------------------------------------------------
__global__ __launch_bounds__(256) void upsample_kernel(
    const float* __restrict__ y, float* __restrict__ yup)
{
    int gid = blockIdx.x * 256 + threadIdx.x;   // 8*32*128*128 = 4194304
    int X = gid & 127;
    int Y = (gid >> 7) & 127;
    int bc = gid >> 14;                          // b*32+c, 0..255
    const float r = (float)(63.0 / 127.0);
    float fy = (float)Y * r;
    float fx = (float)X * r;
    int y0 = (int)fy, x0 = (int)fx;
    int y1 = min(y0 + 1, 63), x1 = min(x0 + 1, 63);
    float wy = fy - (float)y0, wx = fx - (float)x0;
    const float* src = y + (size_t)bc * 4096;
    float v00 = src[y0 * 64 + x0], v01 = src[y0 * 64 + x1];
    float v10 = src[y1 * 64 + x0], v11 = src[y1 * 64 + x1];
    float a  = v00 * (1.f - wy) + v10 * wy;
    float bb = v01 * (1.f - wy) + v11 * wy;
    yup[gid] = a * (1.f - wx) + bb * wx;
}

// ---------------------------------------------------------------------------
// Kernel 4: 3x3 conv, 32->64 channels, SAME padding, writes out channels 64..127
// One thread per pixel, 8 output channels per block (weights via scalar loads)
// ---------------------------------------------------------------------------
__global__ __launch_bounds__(256) void conv3x3_kernel(
    const float* __restrict__ yup, const float* __restrict__ w,
    float* __restrict__ out)
{
    int b = blockIdx.z, ocg = blockIdx.y;
    int pix = blockIdx.x * 256 + threadIdx.x;   // 0..16383
    int yy = pix >> 7, xx = pix & 127;
    const float* src = yup + (size_t)b * 32 * 16384;

    float acc[8];
#pragma unroll
    for (int o = 0; o < 8; ++o) acc[o] = 0.f;

    for (int c = 0; c < 32; ++c) {
        const float* sc_ = src + (size_t)c * 16384;
#pragma unroll
        for (int ky = 0; ky < 3; ++ky) {
            int iy = yy + ky - 1;
            bool oky = (unsigned)iy < 128u;
#pragma unroll
            for (int kx = 0; kx < 3; ++kx) {
                int ix = xx + kx - 1;
                float v = (oky && (unsigned)ix < 128u) ? sc_[iy * 128 + ix] : 0.f;
#pragma unroll
                for (int o = 0; o < 8; ++o)
                    acc[o] = fmaf(w[(((ocg * 8 + o) * 32 + c) * 9) + ky * 3 + kx], v, acc[o]);
            }
        }
    }
#pragma unroll
    for (int o = 0; o < 8; ++o)
        out[((size_t)b * 128 + 64 + ocg * 8 + o) * 16384 + pix] = acc[o];
}

// ---------------------------------------------------------------------------
// Kernel 5: copy primary into out channels 0..63 (float4)
// ---------------------------------------------------------------------------
__global__ __launch_bounds__(256) void copy_primary_kernel(
    const float4* __restrict__ p, float4* __restrict__ out)
{
    int gid = blockIdx.x * 256 + threadIdx.x;   // 0..2097151
    const int chunk = (64 * 16384) / 4;         // 262144 float4 per batch
    int b = gid >> 18;
    int off = gid & (chunk - 1);
    out[(size_t)b * 2 * chunk + off] = p[gid];
}

// ---------------------------------------------------------------------------
extern "C" void kernel_launch(void* const* d_in, const int* in_sizes, int n_in,
                              void* d_out, int out_size, void* d_ws, size_t ws_size,
                              hipStream_t stream)
{
    const float* primary = (const float*)d_in[0];
    const float* cross   = (const float*)d_in[1];
    const float* w_theta = (const float*)d_in[2];
    const float* w_phi   = (const float*)d_in[3];
    const float* w_g     = (const float*)d_in[4];
    const float* w_out   = (const float*)d_in[5];
    float* out = (float*)d_out;

    float* ws = (float*)d_ws;
    float* theta = ws;                       // 8*4096*32 = 1048576
    float* g     = ws + 1048576;             // 1048576
    float* phi   = ws + 2 * 1048576;         // 1048576
    float* y     = ws + 3 * 1048576;         // 1048576
    float* yup   = ws + 4 * 1048576;         // 4194304
    // total 8388608 floats = 33.5 MB

    pool_project_kernel<<<128, 256, 0, stream>>>(primary, cross, w_theta, w_phi, w_g,
                                                 theta, phi, g);
    attn_kernel<<<dim3(64, 8), 256, 0, stream>>>(theta, phi, g, y);
    upsample_kernel<<<16384, 256, 0, stream>>>(y, yup);
    conv3x3_kernel<<<dim3(64, 8, 8), 256, 0, stream>>>(yup, w_out, out);
    copy_primary_kernel<<<8192, 256, 0, stream>>>((const float4*)primary, (float4*)out);
}

// Round 2
// 224.897 us; speedup vs baseline: 3.4177x; 3.4177x over previous
//
#include <hip/hip_runtime.h>
#include <math.h>

typedef _Float16 f16;
typedef f16 f16x8 __attribute__((ext_vector_type(8)));
typedef float f32x4 __attribute__((ext_vector_type(4)));

#define LOG2E 1.44269504088896340736f

// ---------------------------------------------------------------------------
// Kernel 0: reorder conv weights f32 [oc][c][9] -> f16 wT [oc][tap*32 + c]
// ---------------------------------------------------------------------------
__global__ __launch_bounds__(256) void wconv_kernel(
    const float* __restrict__ w, f16* __restrict__ wT)
{
    int id = blockIdx.x * 256 + threadIdx.x;      // < 18432 = 64*288
    int oc = id / 288, k = id % 288;
    int tap = k >> 5, c = k & 31;                 // k = tap*32 + c
    wT[id] = (f16)w[((size_t)oc * 32 + c) * 9 + tap];
}

// ---------------------------------------------------------------------------
// Kernel 1: fused 2x2 avg-pool + three 1x1 projections, f16 outputs.
// theta [b][n][32] (pre-scaled by log2e), phi [b][n][32], gT [b][32][n]
// ---------------------------------------------------------------------------
__global__ __launch_bounds__(256) void pool_project_kernel(
    const float* __restrict__ primary, const float* __restrict__ cross,
    const float* __restrict__ w_theta, const float* __restrict__ w_phi,
    const float* __restrict__ w_g,
    f16* __restrict__ theta, f16* __restrict__ phi, f16* __restrict__ gT)
{
    int gid = blockIdx.x * 256 + threadIdx.x;     // b*4096 + n
    int b = gid >> 12, n = gid & 4095;
    int yy = n >> 6, xx = n & 63;

    size_t base0 = (size_t)b * 64 * 16384 + (size_t)(2 * yy) * 128 + 2 * xx;
    const float* pbase = primary + base0;
    const float* cbase = cross + base0;

    float th[32], ph[32], gg[32];
#pragma unroll
    for (int m = 0; m < 32; ++m) { th[m] = 0.f; ph[m] = 0.f; gg[m] = 0.f; }

    for (int c = 0; c < 64; ++c) {
        float2 p0 = *(const float2*)(pbase + (size_t)c * 16384);
        float2 p1 = *(const float2*)(pbase + (size_t)c * 16384 + 128);
        float2 c0 = *(const float2*)(cbase + (size_t)c * 16384);
        float2 c1 = *(const float2*)(cbase + (size_t)c * 16384 + 128);
        float pdc = 0.25f * ((p0.x + p0.y) + (p1.x + p1.y));
        float cdc = 0.25f * ((c0.x + c0.y) + (c1.x + c1.y));
#pragma unroll
        for (int m = 0; m < 32; ++m) {
            th[m] = fmaf(w_theta[m * 64 + c], cdc, th[m]);
            ph[m] = fmaf(w_phi[m * 64 + c], pdc, ph[m]);
            gg[m] = fmaf(w_g[m * 64 + c], pdc, gg[m]);
        }
    }

    f16* tp = theta + (size_t)gid * 32;
    f16* pp = phi + (size_t)gid * 32;
#pragma unroll
    for (int m0 = 0; m0 < 32; m0 += 8) {
        f16x8 tv, pv;
#pragma unroll
        for (int j = 0; j < 8; ++j) {
            tv[j] = (f16)(th[m0 + j] * LOG2E);   // fold log2(e) into theta
            pv[j] = (f16)ph[m0 + j];
        }
        *(f16x8*)(tp + m0) = tv;
        *(f16x8*)(pp + m0) = pv;
    }
    f16* gp = gT + (size_t)b * 32 * 4096 + n;
#pragma unroll
    for (int m = 0; m < 32; ++m) gp[(size_t)m * 4096] = (f16)gg[m];
}

// ---------------------------------------------------------------------------
// Kernel 2: flash attention with f16 MFMA 16x16x32.
// Per wave: 16 queries, KV blocks of 128. Fragments loaded straight from
// global (contiguous 16B per lane). P round-trips per-wave swizzled LDS.
// ---------------------------------------------------------------------------
__global__ __launch_bounds__(256) void attn_kernel(
    const f16* __restrict__ theta, const f16* __restrict__ phi,
    const f16* __restrict__ gT, float* __restrict__ y)
{
    __shared__ f16 P[4][16 * 128];                // 4 KB per wave
    int t = threadIdx.x;
    int wid = t >> 6, lane = t & 63;
    int g = lane >> 4, c15 = lane & 15;
    int b = blockIdx.y;
    int qb = blockIdx.x * 64 + wid * 16;

    // A operand (theta): A[q][c], q=lane&15, c=(lane>>4)*8+j -> 16B contiguous
    f16x8 a_th = *(const f16x8*)(theta + ((size_t)b * 4096 + qb + c15) * 32 + g * 8);

    f32x4 Y0 = {0.f, 0.f, 0.f, 0.f}, Y1 = {0.f, 0.f, 0.f, 0.f};
    float mrow[4], lrow[4];
#pragma unroll
    for (int r = 0; r < 4; ++r) { mrow[r] = -1e30f; lrow[r] = 0.f; }

    const f16* phiB = phi + (size_t)b * 4096 * 32;
    const f16* gB   = gT  + (size_t)b * 32 * 4096;
    f16* Pw = P[wid];
    int swzW = g << 4;             // write: q>>2 == g
    int swzR = (c15 >> 2) << 4;    // read:  q = c15

    for (int kt = 0; kt < 32; ++kt) {
        int n0 = kt * 128;
        f32x4 s[8];
        f32x4 z = {0.f, 0.f, 0.f, 0.f};
#pragma unroll
        for (int t8 = 0; t8 < 8; ++t8) {
            // B[c][k] = phi_nmajor[k][c]: 16B contiguous per lane
            f16x8 bf = *(const f16x8*)(phiB + (size_t)(n0 + t8 * 16 + c15) * 32 + g * 8);
            s[t8] = __builtin_amdgcn_mfma_f32_16x16x32_f16(a_th, bf, z, 0, 0, 0);
        }
#pragma unroll
        for (int r = 0; r < 4; ++r) {
            float tm = s[0][r];
#pragma unroll
            for (int t8 = 1; t8 < 8; ++t8) tm = fmaxf(tm, s[t8][r]);
            tm = fmaxf(tm, __shfl_xor(tm, 1));
            tm = fmaxf(tm, __shfl_xor(tm, 2));
            tm = fmaxf(tm, __shfl_xor(tm, 4));
            tm = fmaxf(tm, __shfl_xor(tm, 8));
            float nm = fmaxf(mrow[r], tm);
            float scl = __builtin_amdgcn_exp2f(mrow[r] - nm);
            mrow[r] = nm;
            float ps = 0.f;
            int rowbase = (g * 4 + r) * 128;
#pragma unroll
            for (int t8 = 0; t8 < 8; ++t8) {
                float p = __builtin_amdgcn_exp2f(s[t8][r] - nm);
                ps += p;
                Pw[rowbase + ((t8 * 16 + c15) ^ swzW)] = (f16)p;  // conflict-free
            }
            ps += __shfl_xor(ps, 1);
            ps += __shfl_xor(ps, 2);
            ps += __shfl_xor(ps, 4);
            ps += __shfl_xor(ps, 8);
            lrow[r] = lrow[r] * scl + ps;
            Y0[r] *= scl;
            Y1[r] *= scl;
        }
#pragma unroll
        for (int kh = 0; kh < 4; ++kh) {
            f16x8 pa = *(const f16x8*)&Pw[c15 * 128 + ((kh * 32 + g * 8) ^ swzR)];
            f16x8 g0 = *(const f16x8*)(gB + (size_t)c15 * 4096 + n0 + kh * 32 + g * 8);
            f16x8 g1 = *(const f16x8*)(gB + (size_t)(16 + c15) * 4096 + n0 + kh * 32 + g * 8);
            Y0 = __builtin_amdgcn_mfma_f32_16x16x32_f16(pa, g0, Y0, 0, 0, 0);
            Y1 = __builtin_amdgcn_mfma_f32_16x16x32_f16(pa, g1, Y1, 0, 0, 0);
        }
    }
    // D layout: col(m) = lane&15, row(q) = (lane>>4)*4 + r
    float* yb = y + (size_t)b * 32 * 4096 + qb;
#pragma unroll
    for (int r = 0; r < 4; ++r) {
        float inv = 1.f / lrow[r];
        yb[(size_t)c15 * 4096 + g * 4 + r]        = Y0[r] * inv;
        yb[(size_t)(16 + c15) * 4096 + g * 4 + r] = Y1[r] * inv;
    }
}

// ---------------------------------------------------------------------------
// Kernel 3: bilinear upsample x2 align_corners, f32 in -> f16 out, 2 px/thread
// ---------------------------------------------------------------------------
__global__ __launch_bounds__(256) void upsample_kernel(
    const float* __restrict__ y, f16* __restrict__ yup)
{
    int gid = blockIdx.x * 256 + threadIdx.x;     // 2,097,152 threads
    int xi = gid & 63, Y = (gid >> 6) & 127, bc = gid >> 13;
    const float r = 63.0f / 127.0f;
    float fy = (float)Y * r;
    int y0 = (int)fy; int y1 = min(y0 + 1, 63);
    float wy = fy - (float)y0;
    const float* r0 = y + (size_t)bc * 4096 + y0 * 64;
    const float* r1 = y + (size_t)bc * 4096 + y1 * 64;
    union { unsigned int u; f16 h[2]; } pk;
#pragma unroll
    for (int k = 0; k < 2; ++k) {
        int X = 2 * xi + k;
        float fx = (float)X * r;
        int x0 = (int)fx; int x1 = min(x0 + 1, 63);
        float wx = fx - (float)x0;
        float a  = r0[x0] * (1.f - wy) + r1[x0] * wy;
        float bb = r0[x1] * (1.f - wy) + r1[x1] * wy;
        pk.h[k] = (f16)(a * (1.f - wx) + bb * wx);
    }
    *(unsigned int*)&yup[((size_t)bc * 128 + Y) * 128 + 2 * xi] = pk.u;
}

// ---------------------------------------------------------------------------
// Kernel 4: 3x3 conv as implicit GEMM MFMA. M=64 oc, N=256 px (2 rows x 128),
// K=288 tap-major. Input tile staged once per block (zero-padded halo).
// ---------------------------------------------------------------------------
__global__ __launch_bounds__(256) void conv3x3_kernel(
    const f16* __restrict__ yup, const f16* __restrict__ wT,
    float* __restrict__ out)
{
    __shared__ f16 tile[32 * 4 * 132];            // [c][row 0..3][slot 0..131]
    int tY = blockIdx.x, b = blockIdx.y;
    int t = threadIdx.x;

    // zero halo columns (slots 0,1 and 130,131)
    {
        int u = t & 127, c = u >> 2, rr = u & 3;
        int s0 = c * 528 + rr * 132 + ((t < 128) ? 0 : 130);
        *(unsigned int*)&tile[s0] = 0u;
    }
    // stage 4 rows (with y halo) of all 32 channels; x slots shifted by +2
#pragma unroll
    for (int rd = 0; rd < 8; ++rd) {
        int id = rd * 256 + t;                    // 0..2047
        int c = id >> 6, rr = (id >> 4) & 3, seg = id & 15;
        int iy = 2 * tY - 1 + rr;
        uint4 v = make_uint4(0u, 0u, 0u, 0u);
        if ((unsigned)iy < 128u)
            v = *(const uint4*)(yup + (((size_t)b * 32 + c) * 128 + iy) * 128 + seg * 8);
        int base = c * 528 + rr * 132 + 2 + seg * 8;
        *(unsigned int*)&tile[base + 0] = v.x;
        *(unsigned int*)&tile[base + 2] = v.y;
        *(unsigned int*)&tile[base + 4] = v.z;
        *(unsigned int*)&tile[base + 6] = v.w;
    }
    __syncthreads();

    int wid = t >> 6, lane = t & 63, g = lane >> 4, c15 = lane & 15;
    f32x4 acc[4][4];
#pragma unroll
    for (int mt = 0; mt < 4; ++mt)
#pragma unroll
        for (int nt = 0; nt < 4; ++nt) acc[mt][nt] = (f32x4){0.f, 0.f, 0.f, 0.f};

#pragma unroll
    for (int tap = 0; tap < 9; ++tap) {
        const int dy = tap / 3, dx = tap % 3;     // compile-time
        f16x8 a0 = *(const f16x8*)(wT + (size_t)(c15) * 288 + tap * 32 + g * 8);
        f16x8 a1 = *(const f16x8*)(wT + (size_t)(16 + c15) * 288 + tap * 32 + g * 8);
        f16x8 a2 = *(const f16x8*)(wT + (size_t)(32 + c15) * 288 + tap * 32 + g * 8);
        f16x8 a3 = *(const f16x8*)(wT + (size_t)(48 + c15) * 288 + tap * 32 + g * 8);
#pragma unroll
        for (int nt = 0; nt < 4; ++nt) {
            int ntg = wid * 4 + nt;
            int r_out = ntg >> 3, x0 = (ntg & 7) * 16;
            int base = (g * 8) * 528 + (r_out + dy) * 132 + 1 + x0 + c15 + dx;
            f16x8 bf;
#pragma unroll
            for (int j = 0; j < 8; ++j) bf[j] = tile[base + j * 528];
            acc[0][nt] = __builtin_amdgcn_mfma_f32_16x16x32_f16(a0, bf, acc[0][nt], 0, 0, 0);
            acc[1][nt] = __builtin_amdgcn_mfma_f32_16x16x32_f16(a1, bf, acc[1][nt], 0, 0, 0);
            acc[2][nt] = __builtin_amdgcn_mfma_f32_16x16x32_f16(a2, bf, acc[2][nt], 0, 0, 0);
            acc[3][nt] = __builtin_amdgcn_mfma_f32_16x16x32_f16(a3, bf, acc[3][nt], 0, 0, 0);
        }
    }

#pragma unroll
    for (int mt = 0; mt < 4; ++mt)
#pragma unroll
        for (int nt = 0; nt < 4; ++nt) {
            int ntg = wid * 4 + nt;
            int r_out = ntg >> 3, x0 = (ntg & 7) * 16;
            float* ob = out + ((size_t)b * 128 + 64 + mt * 16 + g * 4) * 16384
                            + (2 * tY + r_out) * 128 + x0 + c15;
#pragma unroll
            for (int r = 0; r < 4; ++r)
                ob[(size_t)r * 16384] = acc[mt][nt][r];
        }
}

// ---------------------------------------------------------------------------
// Kernel 5: copy primary into out channels 0..63 (float4)
// ---------------------------------------------------------------------------
__global__ __launch_bounds__(256) void copy_primary_kernel(
    const float4* __restrict__ p, float4* __restrict__ out)
{
    int gid = blockIdx.x * 256 + threadIdx.x;     // 0..2097151
    const int chunk = (64 * 16384) / 4;           // 262144 float4 per batch
    int b = gid >> 18;
    int off = gid & (chunk - 1);
    out[(size_t)b * 2 * chunk + off] = p[gid];
}

// ---------------------------------------------------------------------------
extern "C" void kernel_launch(void* const* d_in, const int* in_sizes, int n_in,
                              void* d_out, int out_size, void* d_ws, size_t ws_size,
                              hipStream_t stream)
{
    const float* primary = (const float*)d_in[0];
    const float* cross   = (const float*)d_in[1];
    const float* w_theta = (const float*)d_in[2];
    const float* w_phi   = (const float*)d_in[3];
    const float* w_g     = (const float*)d_in[4];
    const float* w_out   = (const float*)d_in[5];
    float* out = (float*)d_out;

    char* wsb = (char*)d_ws;
    f16*   wT    = (f16*)(wsb);                              // 36,864 B
    f16*   theta = (f16*)(wsb + (1 << 16));                  // 2 MB
    f16*   phi   = (f16*)(wsb + (1 << 16) + (2u << 20));     // 2 MB
    f16*   gT    = (f16*)(wsb + (1 << 16) + (4u << 20));     // 2 MB
    float* y     = (float*)(wsb + (1 << 16) + (6u << 20));   // 4 MB
    f16*   yup   = (f16*)(wsb + (1 << 16) + (10u << 20));    // 8 MB

    wconv_kernel<<<72, 256, 0, stream>>>(w_out, wT);
    pool_project_kernel<<<128, 256, 0, stream>>>(primary, cross, w_theta, w_phi, w_g,
                                                 theta, phi, gT);
    attn_kernel<<<dim3(64, 8), 256, 0, stream>>>(theta, phi, gT, y);
    upsample_kernel<<<8192, 256, 0, stream>>>(y, yup);
    conv3x3_kernel<<<dim3(64, 8), 256, 0, stream>>>(yup, wT, out);
    copy_primary_kernel<<<8192, 256, 0, stream>>>((const float4*)primary, (float4*)out);
}

// Round 3
// 182.703 us; speedup vs baseline: 4.2070x; 1.2309x over previous
//
#include <hip/hip_runtime.h>
#include <math.h>

typedef _Float16 f16;
typedef f16 f16x8 __attribute__((ext_vector_type(8)));
typedef f16 f16x4 __attribute__((ext_vector_type(4)));
typedef float f32x4 __attribute__((ext_vector_type(4)));

#define LOG2E 1.44269504088896340736f

// ---------------------------------------------------------------------------
// Kernel 0: reorder conv weights f32 [oc][c][9] -> f16 wT [oc][tap*32 + c]
// ---------------------------------------------------------------------------
__global__ __launch_bounds__(256) void wconv_kernel(
    const float* __restrict__ w, f16* __restrict__ wT)
{
    int id = blockIdx.x * 256 + threadIdx.x;      // < 18432 = 64*288
    int oc = id / 288, k = id % 288;
    int tap = k >> 5, c = k & 31;                 // k = tap*32 + c
    wT[id] = (f16)w[((size_t)oc * 32 + c) * 9 + tap];
}

// ---------------------------------------------------------------------------
// Kernel 1: fused 2x2 avg-pool + three 1x1 projections, channel-split x4
// across waves + LDS reduce. theta [b][n][32] (pre-scaled log2e), phi
// [b][n][32], gT [b][32][n].
// ---------------------------------------------------------------------------
__global__ __launch_bounds__(256) void pool_project_kernel(
    const float* __restrict__ primary, const float* __restrict__ cross,
    const float* __restrict__ w_theta, const float* __restrict__ w_phi,
    const float* __restrict__ w_g,
    f16* __restrict__ theta, f16* __restrict__ phi, f16* __restrict__ gT)
{
    __shared__ float red[4][64][33];
    int t = threadIdx.x;
    int cg = t >> 6, nl = t & 63;                 // wave = channel group
    int gid = blockIdx.x * 64 + nl;               // 512 blocks
    int b = gid >> 12, n = gid & 4095;
    int yy = n >> 6, xx = n & 63;

    size_t base0 = (size_t)b * 64 * 16384 + (size_t)(2 * yy) * 128 + 2 * xx
                 + (size_t)cg * 16 * 16384;
    const float* pbase = primary + base0;
    const float* cbase = cross + base0;

    float th[32], ph[32], gg[32];
#pragma unroll
    for (int m = 0; m < 32; ++m) { th[m] = 0.f; ph[m] = 0.f; gg[m] = 0.f; }

#pragma unroll
    for (int ci = 0; ci < 16; ++ci) {
        int c = cg * 16 + ci;
        float2 p0 = *(const float2*)(pbase + (size_t)ci * 16384);
        float2 p1 = *(const float2*)(pbase + (size_t)ci * 16384 + 128);
        float2 c0 = *(const float2*)(cbase + (size_t)ci * 16384);
        float2 c1 = *(const float2*)(cbase + (size_t)ci * 16384 + 128);
        float pdc = 0.25f * ((p0.x + p0.y) + (p1.x + p1.y));
        float cdc = 0.25f * ((c0.x + c0.y) + (c1.x + c1.y));
#pragma unroll
        for (int m = 0; m < 32; ++m) {
            th[m] = fmaf(w_theta[m * 64 + c], cdc, th[m]);
            ph[m] = fmaf(w_phi[m * 64 + c], pdc, ph[m]);
            gg[m] = fmaf(w_g[m * 64 + c], pdc, gg[m]);
        }
    }

    int nl2 = t >> 2, mo = (t & 3) * 8;
    int gbase = blockIdx.x * 64;                  // global n base of block

    // ---- theta ----
#pragma unroll
    for (int m = 0; m < 32; ++m) red[cg][nl][m] = th[m];
    __syncthreads();
    {
        f16x8 hv;
#pragma unroll
        for (int j = 0; j < 8; ++j) {
            float v = red[0][nl2][mo + j] + red[1][nl2][mo + j]
                    + red[2][nl2][mo + j] + red[3][nl2][mo + j];
            hv[j] = (f16)(v * LOG2E);
        }
        *(f16x8*)(theta + (size_t)(gbase + nl2) * 32 + mo) = hv;
    }
    __syncthreads();

    // ---- phi ----
#pragma unroll
    for (int m = 0; m < 32; ++m) red[cg][nl][m] = ph[m];
    __syncthreads();
    {
        f16x8 hv;
#pragma unroll
        for (int j = 0; j < 8; ++j) {
            float v = red[0][nl2][mo + j] + red[1][nl2][mo + j]
                    + red[2][nl2][mo + j] + red[3][nl2][mo + j];
            hv[j] = (f16)v;
        }
        *(f16x8*)(phi + (size_t)(gbase + nl2) * 32 + mo) = hv;
    }
    __syncthreads();

    // ---- g (needs transpose to m-major) ----
#pragma unroll
    for (int m = 0; m < 32; ++m) red[cg][nl][m] = gg[m];
    __syncthreads();
    float vsum[8];
#pragma unroll
    for (int j = 0; j < 8; ++j)
        vsum[j] = red[0][nl2][mo + j] + red[1][nl2][mo + j]
                + red[2][nl2][mo + j] + red[3][nl2][mo + j];
    __syncthreads();
    float (*redS)[33] = red[0];
#pragma unroll
    for (int j = 0; j < 8; ++j) redS[nl2][mo + j] = vsum[j];
    __syncthreads();
    {
        int m = t >> 3, n8 = (t & 7) * 8;
        f16x8 gv;
#pragma unroll
        for (int j = 0; j < 8; ++j) gv[j] = (f16)redS[n8 + j][m];
        int bblk = gbase >> 12, nb = gbase & 4095;
        *(f16x8*)(gT + ((size_t)bblk * 32 + m) * 4096 + nb + n8) = gv;
    }
}

// ---------------------------------------------------------------------------
// Kernel 2: flash attention, f16 MFMA, fixed-base softmax (C=12 folded into
// the QK accumulator init), split-KV x4 for occupancy. Partials are plain
// sums: ypart (f16) and lpart (f32), combined by combine_kernel.
// ---------------------------------------------------------------------------
__global__ __launch_bounds__(256) void attn_kernel(
    const f16* __restrict__ theta, const f16* __restrict__ phi,
    const f16* __restrict__ gT, f16* __restrict__ ypart,
    float* __restrict__ lpart)
{
    __shared__ f16 P[4][16 * 128];                // 4 KB per wave
    int t = threadIdx.x;
    int wid = t >> 6, lane = t & 63;
    int g = lane >> 4, c15 = lane & 15;
    int b = blockIdx.y, sp = blockIdx.z;
    int qb = blockIdx.x * 64 + wid * 16;

    // A operand (theta): A[q][c], q=lane&15, c=(lane>>4)*8+j -> 16B contiguous
    f16x8 a_th = *(const f16x8*)(theta + ((size_t)b * 4096 + qb + c15) * 32 + g * 8);

    f32x4 Y0 = {0.f, 0.f, 0.f, 0.f}, Y1 = {0.f, 0.f, 0.f, 0.f};
    float lsum[4] = {0.f, 0.f, 0.f, 0.f};
    const f32x4 zinit = {-12.f, -12.f, -12.f, -12.f};   // fixed softmax base

    const f16* phiB = phi + (size_t)b * 4096 * 32;
    const f16* gB   = gT  + (size_t)b * 32 * 4096;
    f16* Pw = P[wid];
    int swzW = g << 4;
    int swzR = (c15 >> 2) << 4;

    for (int kt = sp * 8; kt < sp * 8 + 8; ++kt) {
        int n0 = kt * 128;
        f32x4 s[8];
#pragma unroll
        for (int t8 = 0; t8 < 8; ++t8) {
            f16x8 bf = *(const f16x8*)(phiB + (size_t)(n0 + t8 * 16 + c15) * 32 + g * 8);
            s[t8] = __builtin_amdgcn_mfma_f32_16x16x32_f16(a_th, bf, zinit, 0, 0, 0);
        }
#pragma unroll
        for (int r = 0; r < 4; ++r) {
            int rowbase = (g * 4 + r) * 128;
#pragma unroll
            for (int t8 = 0; t8 < 8; ++t8) {
                float p = __builtin_amdgcn_exp2f(fminf(s[t8][r], 15.f));
                lsum[r] += p;
                Pw[rowbase + ((t8 * 16 + c15) ^ swzW)] = (f16)p;
            }
        }
#pragma unroll
        for (int kh = 0; kh < 4; ++kh) {
            f16x8 pa = *(const f16x8*)&Pw[c15 * 128 + ((kh * 32 + g * 8) ^ swzR)];
            f16x8 g0 = *(const f16x8*)(gB + (size_t)c15 * 4096 + n0 + kh * 32 + g * 8);
            f16x8 g1 = *(const f16x8*)(gB + (size_t)(16 + c15) * 4096 + n0 + kh * 32 + g * 8);
            Y0 = __builtin_amdgcn_mfma_f32_16x16x32_f16(pa, g0, Y0, 0, 0, 0);
            Y1 = __builtin_amdgcn_mfma_f32_16x16x32_f16(pa, g1, Y1, 0, 0, 0);
        }
    }

    // reduce l across the 16 lanes of each row group, write partials
#pragma unroll
    for (int r = 0; r < 4; ++r) {
        float v = lsum[r];
        v += __shfl_xor(v, 1);
        v += __shfl_xor(v, 2);
        v += __shfl_xor(v, 4);
        v += __shfl_xor(v, 8);
        if (c15 == 0)
            lpart[((size_t)(sp * 8 + b)) * 4096 + qb + g * 4 + r] = v;
    }
    f16* yp = ypart + ((size_t)(sp * 8 + b) * 32) * 4096 + qb;
#pragma unroll
    for (int r = 0; r < 4; ++r) {
        yp[(size_t)c15 * 4096 + g * 4 + r]        = (f16)Y0[r];
        yp[(size_t)(16 + c15) * 4096 + g * 4 + r] = (f16)Y1[r];
    }
}

// ---------------------------------------------------------------------------
// Kernel 2b: combine split-KV partials: y = sum_s ypart / sum_s lpart
// ---------------------------------------------------------------------------
__global__ __launch_bounds__(256) void combine_kernel(
    const f16* __restrict__ ypart, const float* __restrict__ lpart,
    float* __restrict__ y)
{
    int gid = blockIdx.x * 256 + threadIdx.x;     // 262144 threads, 4 n each
    int n4 = (gid & 1023) * 4;
    int bm = gid >> 10;                           // b*32 + m
    int b = bm >> 5, m = bm & 31;
    float acc0 = 0.f, acc1 = 0.f, acc2 = 0.f, acc3 = 0.f;
    float l0 = 0.f, l1 = 0.f, l2 = 0.f, l3 = 0.f;
#pragma unroll
    for (int s = 0; s < 4; ++s) {
        f16x4 yv = *(const f16x4*)(ypart + ((size_t)(s * 8 + b) * 32 + m) * 4096 + n4);
        float4 lv = *(const float4*)(lpart + ((size_t)(s * 8 + b)) * 4096 + n4);
        acc0 += (float)yv[0]; acc1 += (float)yv[1];
        acc2 += (float)yv[2]; acc3 += (float)yv[3];
        l0 += lv.x; l1 += lv.y; l2 += lv.z; l3 += lv.w;
    }
    float4 o = make_float4(acc0 / l0, acc1 / l1, acc2 / l2, acc3 / l3);
    *(float4*)(y + (size_t)bm * 4096 + n4) = o;
}

// ---------------------------------------------------------------------------
// Kernel 3: bilinear upsample x2 align_corners, f32 in -> f16 out, 2 px/thread
// ---------------------------------------------------------------------------
__global__ __launch_bounds__(256) void upsample_kernel(
    const float* __restrict__ y, f16* __restrict__ yup)
{
    int gid = blockIdx.x * 256 + threadIdx.x;     // 2,097,152 threads
    int xi = gid & 63, Y = (gid >> 6) & 127, bc = gid >> 13;
    const float r = 63.0f / 127.0f;
    float fy = (float)Y * r;
    int y0 = (int)fy; int y1 = min(y0 + 1, 63);
    float wy = fy - (float)y0;
    const float* r0 = y + (size_t)bc * 4096 + y0 * 64;
    const float* r1 = y + (size_t)bc * 4096 + y1 * 64;
    union { unsigned int u; f16 h[2]; } pk;
#pragma unroll
    for (int k = 0; k < 2; ++k) {
        int X = 2 * xi + k;
        float fx = (float)X * r;
        int x0 = (int)fx; int x1 = min(x0 + 1, 63);
        float wx = fx - (float)x0;
        float a  = r0[x0] * (1.f - wy) + r1[x0] * wy;
        float bb = r0[x1] * (1.f - wy) + r1[x1] * wy;
        pk.h[k] = (f16)(a * (1.f - wx) + bb * wx);
    }
    *(unsigned int*)&yup[((size_t)bc * 128 + Y) * 128 + 2 * xi] = pk.u;
}

// ---------------------------------------------------------------------------
// Kernel 4: 3x3 conv as implicit GEMM MFMA. M=64 oc, N=256 px (2 rows x 128),
// K=288 tap-major. Input tile staged once per block (zero-padded halo).
// ---------------------------------------------------------------------------
__global__ __launch_bounds__(256) void conv3x3_kernel(
    const f16* __restrict__ yup, const f16* __restrict__ wT,
    float* __restrict__ out)
{
    __shared__ f16 tile[32 * 4 * 132];            // [c][row 0..3][slot 0..131]
    int tY = blockIdx.x, b = blockIdx.y;
    int t = threadIdx.x;

    // zero halo columns (slots 0,1 and 130,131)
    {
        int u = t & 127, c = u >> 2, rr = u & 3;
        int s0 = c * 528 + rr * 132 + ((t < 128) ? 0 : 130);
        *(unsigned int*)&tile[s0] = 0u;
    }
#pragma unroll
    for (int rd = 0; rd < 8; ++rd) {
        int id = rd * 256 + t;                    // 0..2047
        int c = id >> 6, rr = (id >> 4) & 3, seg = id & 15;
        int iy = 2 * tY - 1 + rr;
        uint4 v = make_uint4(0u, 0u, 0u, 0u);
        if ((unsigned)iy < 128u)
            v = *(const uint4*)(yup + (((size_t)b * 32 + c) * 128 + iy) * 128 + seg * 8);
        int base = c * 528 + rr * 132 + 2 + seg * 8;
        *(unsigned int*)&tile[base + 0] = v.x;
        *(unsigned int*)&tile[base + 2] = v.y;
        *(unsigned int*)&tile[base + 4] = v.z;
        *(unsigned int*)&tile[base + 6] = v.w;
    }
    __syncthreads();

    int wid = t >> 6, lane = t & 63, g = lane >> 4, c15 = lane & 15;
    f32x4 acc[4][4];
#pragma unroll
    for (int mt = 0; mt < 4; ++mt)
#pragma unroll
        for (int nt = 0; nt < 4; ++nt) acc[mt][nt] = (f32x4){0.f, 0.f, 0.f, 0.f};

#pragma unroll
    for (int tap = 0; tap < 9; ++tap) {
        const int dy = tap / 3, dx = tap % 3;     // compile-time
        f16x8 a0 = *(const f16x8*)(wT + (size_t)(c15) * 288 + tap * 32 + g * 8);
        f16x8 a1 = *(const f16x8*)(wT + (size_t)(16 + c15) * 288 + tap * 32 + g * 8);
        f16x8 a2 = *(const f16x8*)(wT + (size_t)(32 + c15) * 288 + tap * 32 + g * 8);
        f16x8 a3 = *(const f16x8*)(wT + (size_t)(48 + c15) * 288 + tap * 32 + g * 8);
#pragma unroll
        for (int nt = 0; nt < 4; ++nt) {
            int ntg = wid * 4 + nt;
            int r_out = ntg >> 3, x0 = (ntg & 7) * 16;
            int base = (g * 8) * 528 + (r_out + dy) * 132 + 1 + x0 + c15 + dx;
            f16x8 bf;
#pragma unroll
            for (int j = 0; j < 8; ++j) bf[j] = tile[base + j * 528];
            acc[0][nt] = __builtin_amdgcn_mfma_f32_16x16x32_f16(a0, bf, acc[0][nt], 0, 0, 0);
            acc[1][nt] = __builtin_amdgcn_mfma_f32_16x16x32_f16(a1, bf, acc[1][nt], 0, 0, 0);
            acc[2][nt] = __builtin_amdgcn_mfma_f32_16x16x32_f16(a2, bf, acc[2][nt], 0, 0, 0);
            acc[3][nt] = __builtin_amdgcn_mfma_f32_16x16x32_f16(a3, bf, acc[3][nt], 0, 0, 0);
        }
    }

#pragma unroll
    for (int mt = 0; mt < 4; ++mt)
#pragma unroll
        for (int nt = 0; nt < 4; ++nt) {
            int ntg = wid * 4 + nt;
            int r_out = ntg >> 3, x0 = (ntg & 7) * 16;
            float* ob = out + ((size_t)b * 128 + 64 + mt * 16 + g * 4) * 16384
                            + (2 * tY + r_out) * 128 + x0 + c15;
#pragma unroll
            for (int r = 0; r < 4; ++r)
                ob[(size_t)r * 16384] = acc[mt][nt][r];
        }
}

// ---------------------------------------------------------------------------
// Kernel 5: copy primary into out channels 0..63 (float4)
// ---------------------------------------------------------------------------
__global__ __launch_bounds__(256) void copy_primary_kernel(
    const float4* __restrict__ p, float4* __restrict__ out)
{
    int gid = blockIdx.x * 256 + threadIdx.x;     // 0..2097151
    const int chunk = (64 * 16384) / 4;           // 262144 float4 per batch
    int b = gid >> 18;
    int off = gid & (chunk - 1);
    out[(size_t)b * 2 * chunk + off] = p[gid];
}

// ---------------------------------------------------------------------------
extern "C" void kernel_launch(void* const* d_in, const int* in_sizes, int n_in,
                              void* d_out, int out_size, void* d_ws, size_t ws_size,
                              hipStream_t stream)
{
    const float* primary = (const float*)d_in[0];
    const float* cross   = (const float*)d_in[1];
    const float* w_theta = (const float*)d_in[2];
    const float* w_phi   = (const float*)d_in[3];
    const float* w_g     = (const float*)d_in[4];
    const float* w_out   = (const float*)d_in[5];
    float* out = (float*)d_out;

    char* wsb = (char*)d_ws;
    f16*   wT    = (f16*)(wsb);                               // 64 KB region
    f16*   theta = (f16*)(wsb + (1u << 16));                  // 2 MB
    f16*   phi   = (f16*)(wsb + (1u << 16) + (2u << 20));     // 2 MB
    f16*   gT    = (f16*)(wsb + (1u << 16) + (4u << 20));     // 2 MB
    float* y     = (float*)(wsb + (1u << 16) + (6u << 20));   // 4 MB
    f16*   yup   = (f16*)(wsb + (1u << 16) + (10u << 20));    // 8 MB
    f16*   ypart = (f16*)(wsb + (1u << 16) + (18u << 20));    // 8 MB
    float* lpart = (float*)(wsb + (1u << 16) + (26u << 20));  // 512 KB

    wconv_kernel<<<72, 256, 0, stream>>>(w_out, wT);
    pool_project_kernel<<<512, 256, 0, stream>>>(primary, cross, w_theta, w_phi, w_g,
                                                 theta, phi, gT);
    attn_kernel<<<dim3(64, 8, 4), 256, 0, stream>>>(theta, phi, gT, ypart, lpart);
    combine_kernel<<<1024, 256, 0, stream>>>(ypart, lpart, y);
    upsample_kernel<<<8192, 256, 0, stream>>>(y, yup);
    conv3x3_kernel<<<dim3(64, 8), 256, 0, stream>>>(yup, wT, out);
    copy_primary_kernel<<<8192, 256, 0, stream>>>((const float4*)primary, (float4*)out);
}

// Round 5
// 173.647 us; speedup vs baseline: 4.4264x; 1.0522x over previous
//
#include <hip/hip_runtime.h>
#include <math.h>

typedef _Float16 f16;
typedef f16 f16x8 __attribute__((ext_vector_type(8)));
typedef f16 f16x4 __attribute__((ext_vector_type(4)));
typedef __fp16 fp16x2 __attribute__((ext_vector_type(2)));
typedef float f32x4 __attribute__((ext_vector_type(4)));

#define LOG2E 1.44269504088896340736f

// ---------------------------------------------------------------------------
// Kernel 0: reorder conv weights f32 [oc][c][9] -> f16 wT [oc][tap*32 + c]
// ---------------------------------------------------------------------------
__global__ __launch_bounds__(256) void wconv_kernel(
    const float* __restrict__ w, f16* __restrict__ wT)
{
    int id = blockIdx.x * 256 + threadIdx.x;      // < 18432 = 64*288
    int oc = id / 288, k = id % 288;
    int tap = k >> 5, c = k & 31;                 // k = tap*32 + c
    wT[id] = (f16)w[((size_t)oc * 32 + c) * 9 + tap];
}

// ---------------------------------------------------------------------------
// Kernel 1: fused 2x2 avg-pool + three 1x1 projections, channel-split x4
// across waves + LDS reduce. theta [b][n][32] (pre-scaled log2e), phi
// [b][n][32], gT [b][32][n].
// ---------------------------------------------------------------------------
__global__ __launch_bounds__(256) void pool_project_kernel(
    const float* __restrict__ primary, const float* __restrict__ cross,
    const float* __restrict__ w_theta, const float* __restrict__ w_phi,
    const float* __restrict__ w_g,
    f16* __restrict__ theta, f16* __restrict__ phi, f16* __restrict__ gT)
{
    __shared__ float red[4][64][33];
    int t = threadIdx.x;
    int cg = t >> 6, nl = t & 63;                 // wave = channel group
    int gid = blockIdx.x * 64 + nl;               // 512 blocks
    int b = gid >> 12, n = gid & 4095;
    int yy = n >> 6, xx = n & 63;

    size_t base0 = (size_t)b * 64 * 16384 + (size_t)(2 * yy) * 128 + 2 * xx
                 + (size_t)cg * 16 * 16384;
    const float* pbase = primary + base0;
    const float* cbase = cross + base0;

    float th[32], ph[32], gg[32];
#pragma unroll
    for (int m = 0; m < 32; ++m) { th[m] = 0.f; ph[m] = 0.f; gg[m] = 0.f; }

#pragma unroll
    for (int ci = 0; ci < 16; ++ci) {
        int c = cg * 16 + ci;
        float2 p0 = *(const float2*)(pbase + (size_t)ci * 16384);
        float2 p1 = *(const float2*)(pbase + (size_t)ci * 16384 + 128);
        float2 c0 = *(const float2*)(cbase + (size_t)ci * 16384);
        float2 c1 = *(const float2*)(cbase + (size_t)ci * 16384 + 128);
        float pdc = 0.25f * ((p0.x + p0.y) + (p1.x + p1.y));
        float cdc = 0.25f * ((c0.x + c0.y) + (c1.x + c1.y));
#pragma unroll
        for (int m = 0; m < 32; ++m) {
            th[m] = fmaf(w_theta[m * 64 + c], cdc, th[m]);
            ph[m] = fmaf(w_phi[m * 64 + c], pdc, ph[m]);
            gg[m] = fmaf(w_g[m * 64 + c], pdc, gg[m]);
        }
    }

    int nl2 = t >> 2, mo = (t & 3) * 8;
    int gbase = blockIdx.x * 64;                  // global n base of block

    // ---- theta ----
#pragma unroll
    for (int m = 0; m < 32; ++m) red[cg][nl][m] = th[m];
    __syncthreads();
    {
        f16x8 hv;
#pragma unroll
        for (int j = 0; j < 8; ++j) {
            float v = red[0][nl2][mo + j] + red[1][nl2][mo + j]
                    + red[2][nl2][mo + j] + red[3][nl2][mo + j];
            hv[j] = (f16)(v * LOG2E);
        }
        *(f16x8*)(theta + (size_t)(gbase + nl2) * 32 + mo) = hv;
    }
    __syncthreads();

    // ---- phi ----
#pragma unroll
    for (int m = 0; m < 32; ++m) red[cg][nl][m] = ph[m];
    __syncthreads();
    {
        f16x8 hv;
#pragma unroll
        for (int j = 0; j < 8; ++j) {
            float v = red[0][nl2][mo + j] + red[1][nl2][mo + j]
                    + red[2][nl2][mo + j] + red[3][nl2][mo + j];
            hv[j] = (f16)v;
        }
        *(f16x8*)(phi + (size_t)(gbase + nl2) * 32 + mo) = hv;
    }
    __syncthreads();

    // ---- g (needs transpose to m-major) ----
#pragma unroll
    for (int m = 0; m < 32; ++m) red[cg][nl][m] = gg[m];
    __syncthreads();
    float vsum[8];
#pragma unroll
    for (int j = 0; j < 8; ++j)
        vsum[j] = red[0][nl2][mo + j] + red[1][nl2][mo + j]
                + red[2][nl2][mo + j] + red[3][nl2][mo + j];
    __syncthreads();
    float (*redS)[33] = red[0];
#pragma unroll
    for (int j = 0; j < 8; ++j) redS[nl2][mo + j] = vsum[j];
    __syncthreads();
    {
        int m = t >> 3, n8 = (t & 7) * 8;
        f16x8 gv;
#pragma unroll
        for (int j = 0; j < 8; ++j) gv[j] = (f16)redS[n8 + j][m];
        int bblk = gbase >> 12, nb = gbase & 4095;
        *(f16x8*)(gT + ((size_t)bblk * 32 + m) * 4096 + nb + n8) = gv;
    }
}

// ---------------------------------------------------------------------------
// Kernel 2: flash attention, f16 MFMA, fixed-base softmax (C=12 folded into
// QK accumulator init), split-KV x4.  Swapped QK (S^T = mfma(phi, theta))
// makes q lane-local; P reaches the PV A-operand via an in-register
// bit-permutation transpose (shfl_xor 16/48) -- no LDS at all.
// ---------------------------------------------------------------------------
__global__ __launch_bounds__(256) void attn_kernel(
    const f16* __restrict__ theta, const f16* __restrict__ phi,
    const f16* __restrict__ gT, f16* __restrict__ ypart,
    float* __restrict__ lpart)
{
    int t = threadIdx.x;
    int wid = t >> 6, lane = t & 63;
    int g = lane >> 4, c15 = lane & 15;
    int b = blockIdx.y, sp = blockIdx.z;
    int qb = blockIdx.x * 64 + wid * 16;

    // theta frag: B[c][q], q = lane&15, c = (lane>>4)*8+j -> 16B contiguous
    f16x8 a_th = *(const f16x8*)(theta + ((size_t)b * 4096 + qb + c15) * 32 + g * 8);

    f32x4 Y0 = {0.f, 0.f, 0.f, 0.f}, Y1 = {0.f, 0.f, 0.f, 0.f};
    float lsum = 0.f;
    const f32x4 zinit = {-12.f, -12.f, -12.f, -12.f};   // fixed softmax base

    const f16* phiB = phi + (size_t)b * 4096 * 32;
    const f16* gB   = gT  + (size_t)b * 32 * 4096;

    const int ktbeg = sp * 8, ktend = sp * 8 + 8;
    bool gl = (g & 1) != 0;               // lane bit g0
    bool keep2 = (g == 0) || (g == 3);    // fixed points of lane-bit swap

    // prologue: phi frags for first kt
    f16x8 bf[8];
#pragma unroll
    for (int t8 = 0; t8 < 8; ++t8)
        bf[t8] = *(const f16x8*)(phiB + (size_t)(ktbeg * 128 + t8 * 16 + c15) * 32 + g * 8);

    for (int kt = ktbeg; kt < ktend; ++kt) {
        int n0 = kt * 128;
        // QK^T swapped: s[t8][r] = S[k = t8*16 + g*4 + r][q = c15] - 12
        f32x4 s[8];
#pragma unroll
        for (int t8 = 0; t8 < 8; ++t8)
            s[t8] = __builtin_amdgcn_mfma_f32_16x16x32_f16(bf[t8], a_th, zinit, 0, 0, 0);

        // prefetch phi frags for next kt (registers, overlaps softmax VALU)
        int ktn = (kt + 1 < ktend) ? kt + 1 : kt;
        int n0n = ktn * 128;
        f16x8 bfn[8];
#pragma unroll
        for (int t8 = 0; t8 < 8; ++t8)
            bfn[t8] = *(const f16x8*)(phiB + (size_t)(n0n + t8 * 16 + c15) * 32 + g * 8);

        // exp2 + pack to f16 pairs: h[t8][w2] = P[k=t8*16+g*4+2w2 (+1)][q]
        unsigned int h[8][2];
#pragma unroll
        for (int t8 = 0; t8 < 8; ++t8) {
#pragma unroll
            for (int w2 = 0; w2 < 2; ++w2) {
                float p0 = __builtin_amdgcn_exp2f(s[t8][2 * w2]);
                float p1 = __builtin_amdgcn_exp2f(s[t8][2 * w2 + 1]);
                lsum += p0 + p1;
                union { fp16x2 v; unsigned int u; } cvt;
                cvt.v = __builtin_amdgcn_cvt_pkrtz(p0, p1);
                h[t8][w2] = cvt.u;
            }
        }

        // in-register transpose + PV
#pragma unroll
        for (int ks = 0; ks < 4; ++ks) {
            // step 1: swap lane bit g0 with reg bit par (partner lane^16)
            unsigned int c0[2], c1[2];
#pragma unroll
            for (int w2 = 0; w2 < 2; ++w2) {
                unsigned int a0 = h[2 * ks][w2], a1 = h[2 * ks + 1][w2];
                unsigned int snd = gl ? a0 : a1;
                unsigned int rec = (unsigned int)__shfl_xor((int)snd, 16);
                c0[w2] = gl ? rec : a0;
                c1[w2] = gl ? a1 : rec;
            }
            // step 2: swap lane bits g1<->g0 (partner lane^48; g=0,3 fixed)
            unsigned int pw[4] = {c0[0], c0[1], c1[0], c1[1]};
            union { unsigned int u[4]; f16x8 v; } pa;
#pragma unroll
            for (int i = 0; i < 4; ++i) {
                unsigned int tsw = (unsigned int)__shfl_xor((int)pw[i], 48);
                pa.u[i] = keep2 ? pw[i] : tsw;
            }
            f16x8 g0 = *(const f16x8*)(gB + (size_t)c15 * 4096 + n0 + ks * 32 + g * 8);
            f16x8 g1 = *(const f16x8*)(gB + (size_t)(16 + c15) * 4096 + n0 + ks * 32 + g * 8);
            Y0 = __builtin_amdgcn_mfma_f32_16x16x32_f16(pa.v, g0, Y0, 0, 0, 0);
            Y1 = __builtin_amdgcn_mfma_f32_16x16x32_f16(pa.v, g1, Y1, 0, 0, 0);
        }
#pragma unroll
        for (int t8 = 0; t8 < 8; ++t8) bf[t8] = bfn[t8];
    }

    // l: per-lane partial is for q = c15; reduce across the 4 g-groups
    lsum += __shfl_xor(lsum, 16);
    lsum += __shfl_xor(lsum, 32);
    if (g == 0)
        lpart[((size_t)(sp * 8 + b)) * 4096 + qb + c15] = lsum;

    // Y: D[q][m]: col(m)=lane&15, row(q)=g*4+r
    f16* yp = ypart + ((size_t)(sp * 8 + b) * 32) * 4096 + qb;
#pragma unroll
    for (int r = 0; r < 4; ++r) {
        yp[(size_t)c15 * 4096 + g * 4 + r]        = (f16)Y0[r];
        yp[(size_t)(16 + c15) * 4096 + g * 4 + r] = (f16)Y1[r];
    }
}

// ---------------------------------------------------------------------------
// Kernel 2b: combine split-KV partials: y = sum_s ypart / sum_s lpart
// ---------------------------------------------------------------------------
__global__ __launch_bounds__(256) void combine_kernel(
    const f16* __restrict__ ypart, const float* __restrict__ lpart,
    float* __restrict__ y)
{
    int gid = blockIdx.x * 256 + threadIdx.x;     // 262144 threads, 4 n each
    int n4 = (gid & 1023) * 4;
    int bm = gid >> 10;                           // b*32 + m
    int b = bm >> 5, m = bm & 31;
    float acc0 = 0.f, acc1 = 0.f, acc2 = 0.f, acc3 = 0.f;
    float l0 = 0.f, l1 = 0.f, l2 = 0.f, l3 = 0.f;
#pragma unroll
    for (int s = 0; s < 4; ++s) {
        f16x4 yv = *(const f16x4*)(ypart + ((size_t)(s * 8 + b) * 32 + m) * 4096 + n4);
        float4 lv = *(const float4*)(lpart + ((size_t)(s * 8 + b)) * 4096 + n4);
        acc0 += (float)yv[0]; acc1 += (float)yv[1];
        acc2 += (float)yv[2]; acc3 += (float)yv[3];
        l0 += lv.x; l1 += lv.y; l2 += lv.z; l3 += lv.w;
    }
    float4 o = make_float4(acc0 / l0, acc1 / l1, acc2 / l2, acc3 / l3);
    *(float4*)(y + (size_t)bm * 4096 + n4) = o;
}

// ---------------------------------------------------------------------------
// Kernel 3: bilinear upsample x2 align_corners, f32 in -> f16 out, 2 px/thread
// ---------------------------------------------------------------------------
__global__ __launch_bounds__(256) void upsample_kernel(
    const float* __restrict__ y, f16* __restrict__ yup)
{
    int gid = blockIdx.x * 256 + threadIdx.x;     // 2,097,152 threads
    int xi = gid & 63, Y = (gid >> 6) & 127, bc = gid >> 13;
    const float r = 63.0f / 127.0f;
    float fy = (float)Y * r;
    int y0 = (int)fy; int y1 = min(y0 + 1, 63);
    float wy = fy - (float)y0;
    const float* r0 = y + (size_t)bc * 4096 + y0 * 64;
    const float* r1 = y + (size_t)bc * 4096 + y1 * 64;
    union { unsigned int u; f16 h[2]; } pk;
#pragma unroll
    for (int k = 0; k < 2; ++k) {
        int X = 2 * xi + k;
        float fx = (float)X * r;
        int x0 = (int)fx; int x1 = min(x0 + 1, 63);
        float wx = fx - (float)x0;
        float a  = r0[x0] * (1.f - wy) + r1[x0] * wy;
        float bb = r0[x1] * (1.f - wy) + r1[x1] * wy;
        pk.h[k] = (f16)(a * (1.f - wx) + bb * wx);
    }
    *(unsigned int*)&yup[((size_t)bc * 128 + Y) * 128 + 2 * xi] = pk.u;
}

// ---------------------------------------------------------------------------
// Kernel 4: 3x3 conv as implicit GEMM MFMA. M=64 oc, N=256 px (2 rows x 128),
// K=288 tap-major. Input tile staged once per block (zero-padded halo).
// ---------------------------------------------------------------------------
__global__ __launch_bounds__(256) void conv3x3_kernel(
    const f16* __restrict__ yup, const f16* __restrict__ wT,
    float* __restrict__ out)
{
    __shared__ f16 tile[32 * 4 * 132];            // [c][row 0..3][slot 0..131]
    int tY = blockIdx.x, b = blockIdx.y;
    int t = threadIdx.x;

    // zero halo columns (slots 0,1 and 130,131)
    {
        int u = t & 127, c = u >> 2, rr = u & 3;
        int s0 = c * 528 + rr * 132 + ((t < 128) ? 0 : 130);
        *(unsigned int*)&tile[s0] = 0u;
    }
#pragma unroll
    for (int rd = 0; rd < 8; ++rd) {
        int id = rd * 256 + t;                    // 0..2047
        int c = id >> 6, rr = (id >> 4) & 3, seg = id & 15;
        int iy = 2 * tY - 1 + rr;
        uint4 v = make_uint4(0u, 0u, 0u, 0u);
        if ((unsigned)iy < 128u)
            v = *(const uint4*)(yup + (((size_t)b * 32 + c) * 128 + iy) * 128 + seg * 8);
        int base = c * 528 + rr * 132 + 2 + seg * 8;
        *(unsigned int*)&tile[base + 0] = v.x;
        *(unsigned int*)&tile[base + 2] = v.y;
        *(unsigned int*)&tile[base + 4] = v.z;
        *(unsigned int*)&tile[base + 6] = v.w;
    }
    __syncthreads();

    int wid = t >> 6, lane = t & 63, g = lane >> 4, c15 = lane & 15;
    f32x4 acc[4][4];
#pragma unroll
    for (int mt = 0; mt < 4; ++mt)
#pragma unroll
        for (int nt = 0; nt < 4; ++nt) acc[mt][nt] = (f32x4){0.f, 0.f, 0.f, 0.f};

#pragma unroll
    for (int tap = 0; tap < 9; ++tap) {
        const int dy = tap / 3, dx = tap % 3;     // compile-time
        f16x8 a0 = *(const f16x8*)(wT + (size_t)(c15) * 288 + tap * 32 + g * 8);
        f16x8 a1 = *(const f16x8*)(wT + (size_t)(16 + c15) * 288 + tap * 32 + g * 8);
        f16x8 a2 = *(const f16x8*)(wT + (size_t)(32 + c15) * 288 + tap * 32 + g * 8);
        f16x8 a3 = *(const f16x8*)(wT + (size_t)(48 + c15) * 288 + tap * 32 + g * 8);
#pragma unroll
        for (int nt = 0; nt < 4; ++nt) {
            int ntg = wid * 4 + nt;
            int r_out = ntg >> 3, x0 = (ntg & 7) * 16;
            int base = (g * 8) * 528 + (r_out + dy) * 132 + 1 + x0 + c15 + dx;
            f16x8 bf;
#pragma unroll
            for (int j = 0; j < 8; ++j) bf[j] = tile[base + j * 528];
            acc[0][nt] = __builtin_amdgcn_mfma_f32_16x16x32_f16(a0, bf, acc[0][nt], 0, 0, 0);
            acc[1][nt] = __builtin_amdgcn_mfma_f32_16x16x32_f16(a1, bf, acc[1][nt], 0, 0, 0);
            acc[2][nt] = __builtin_amdgcn_mfma_f32_16x16x32_f16(a2, bf, acc[2][nt], 0, 0, 0);
            acc[3][nt] = __builtin_amdgcn_mfma_f32_16x16x32_f16(a3, bf, acc[3][nt], 0, 0, 0);
        }
    }

#pragma unroll
    for (int mt = 0; mt < 4; ++mt)
#pragma unroll
        for (int nt = 0; nt < 4; ++nt) {
            int ntg = wid * 4 + nt;
            int r_out = ntg >> 3, x0 = (ntg & 7) * 16;
            float* ob = out + ((size_t)b * 128 + 64 + mt * 16 + g * 4) * 16384
                            + (2 * tY + r_out) * 128 + x0 + c15;
#pragma unroll
            for (int r = 0; r < 4; ++r)
                ob[(size_t)r * 16384] = acc[mt][nt][r];
        }
}

// ---------------------------------------------------------------------------
// Kernel 5: copy primary into out channels 0..63 (float4)
// ---------------------------------------------------------------------------
__global__ __launch_bounds__(256) void copy_primary_kernel(
    const float4* __restrict__ p, float4* __restrict__ out)
{
    int gid = blockIdx.x * 256 + threadIdx.x;     // 0..2097151
    const int chunk = (64 * 16384) / 4;           // 262144 float4 per batch
    int b = gid >> 18;
    int off = gid & (chunk - 1);
    out[(size_t)b * 2 * chunk + off] = p[gid];
}

// ---------------------------------------------------------------------------
extern "C" void kernel_launch(void* const* d_in, const int* in_sizes, int n_in,
                              void* d_out, int out_size, void* d_ws, size_t ws_size,
                              hipStream_t stream)
{
    const float* primary = (const float*)d_in[0];
    const float* cross   = (const float*)d_in[1];
    const float* w_theta = (const float*)d_in[2];
    const float* w_phi   = (const float*)d_in[3];
    const float* w_g     = (const float*)d_in[4];
    const float* w_out   = (const float*)d_in[5];
    float* out = (float*)d_out;

    char* wsb = (char*)d_ws;
    f16*   wT    = (f16*)(wsb);                               // 64 KB region
    f16*   theta = (f16*)(wsb + (1u << 16));                  // 2 MB
    f16*   phi   = (f16*)(wsb + (1u << 16) + (2u << 20));     // 2 MB
    f16*   gT    = (f16*)(wsb + (1u << 16) + (4u << 20));     // 2 MB
    float* y     = (float*)(wsb + (1u << 16) + (6u << 20));   // 4 MB
    f16*   yup   = (f16*)(wsb + (1u << 16) + (10u << 20));    // 8 MB
    f16*   ypart = (f16*)(wsb + (1u << 16) + (18u << 20));    // 8 MB
    float* lpart = (float*)(wsb + (1u << 16) + (26u << 20));  // 512 KB

    wconv_kernel<<<72, 256, 0, stream>>>(w_out, wT);
    pool_project_kernel<<<512, 256, 0, stream>>>(primary, cross, w_theta, w_phi, w_g,
                                                 theta, phi, gT);
    attn_kernel<<<dim3(64, 8, 4), 256, 0, stream>>>(theta, phi, gT, ypart, lpart);
    combine_kernel<<<1024, 256, 0, stream>>>(ypart, lpart, y);
    upsample_kernel<<<8192, 256, 0, stream>>>(y, yup);
    conv3x3_kernel<<<dim3(64, 8), 256, 0, stream>>>(yup, wT, out);
    copy_primary_kernel<<<8192, 256, 0, stream>>>((const float4*)primary, (float4*)out);
}

// Round 6
// 171.514 us; speedup vs baseline: 4.4814x; 1.0124x over previous
//
#include <hip/hip_runtime.h>
#include <math.h>

typedef _Float16 f16;
typedef f16 f16x8 __attribute__((ext_vector_type(8)));
typedef f16 f16x4 __attribute__((ext_vector_type(4)));
typedef __fp16 fp16x2 __attribute__((ext_vector_type(2)));
typedef float f32x4 __attribute__((ext_vector_type(4)));

#define LOG2E 1.44269504088896340736f

// ---------------------------------------------------------------------------
// Kernel 0: reorder conv weights f32 [oc][c][9] -> f16 wT [oc][tap*32 + c]
// ---------------------------------------------------------------------------
__global__ __launch_bounds__(256) void wconv_kernel(
    const float* __restrict__ w, f16* __restrict__ wT)
{
    int id = blockIdx.x * 256 + threadIdx.x;      // < 18432 = 64*288
    int oc = id / 288, k = id % 288;
    int tap = k >> 5, c = k & 31;                 // k = tap*32 + c
    wT[id] = (f16)w[((size_t)oc * 32 + c) * 9 + tap];
}

// ---------------------------------------------------------------------------
// Kernel 1: fused 2x2 avg-pool + three 1x1 projections, channel-split x4
// across waves + LDS reduce. theta [b][n][32] (pre-scaled log2e), phi
// [b][n][32], gP [b][32][n_permuted]: within each 32-block of n, position
// g*8 + h*4 + jj holds value at h*16 + g*4 + jj  (matches the lane-local
// k-order of the swapped-QK MFMA output, so attention PV needs no shuffle).
// ---------------------------------------------------------------------------
__global__ __launch_bounds__(256) void pool_project_kernel(
    const float* __restrict__ primary, const float* __restrict__ cross,
    const float* __restrict__ w_theta, const float* __restrict__ w_phi,
    const float* __restrict__ w_g,
    f16* __restrict__ theta, f16* __restrict__ phi, f16* __restrict__ gP)
{
    __shared__ float red[4][64][33];
    int t = threadIdx.x;
    int cg = t >> 6, nl = t & 63;                 // wave = channel group
    int gid = blockIdx.x * 64 + nl;               // 512 blocks
    int b = gid >> 12, n = gid & 4095;
    int yy = n >> 6, xx = n & 63;

    size_t base0 = (size_t)b * 64 * 16384 + (size_t)(2 * yy) * 128 + 2 * xx
                 + (size_t)cg * 16 * 16384;
    const float* pbase = primary + base0;
    const float* cbase = cross + base0;

    float th[32], ph[32], gg[32];
#pragma unroll
    for (int m = 0; m < 32; ++m) { th[m] = 0.f; ph[m] = 0.f; gg[m] = 0.f; }

#pragma unroll
    for (int ci = 0; ci < 16; ++ci) {
        int c = cg * 16 + ci;
        float2 p0 = *(const float2*)(pbase + (size_t)ci * 16384);
        float2 p1 = *(const float2*)(pbase + (size_t)ci * 16384 + 128);
        float2 c0 = *(const float2*)(cbase + (size_t)ci * 16384);
        float2 c1 = *(const float2*)(cbase + (size_t)ci * 16384 + 128);
        float pdc = 0.25f * ((p0.x + p0.y) + (p1.x + p1.y));
        float cdc = 0.25f * ((c0.x + c0.y) + (c1.x + c1.y));
#pragma unroll
        for (int m = 0; m < 32; ++m) {
            th[m] = fmaf(w_theta[m * 64 + c], cdc, th[m]);
            ph[m] = fmaf(w_phi[m * 64 + c], pdc, ph[m]);
            gg[m] = fmaf(w_g[m * 64 + c], pdc, gg[m]);
        }
    }

    int nl2 = t >> 2, mo = (t & 3) * 8;
    int gbase = blockIdx.x * 64;                  // global n base of block

    // ---- theta ----
#pragma unroll
    for (int m = 0; m < 32; ++m) red[cg][nl][m] = th[m];
    __syncthreads();
    {
        f16x8 hv;
#pragma unroll
        for (int j = 0; j < 8; ++j) {
            float v = red[0][nl2][mo + j] + red[1][nl2][mo + j]
                    + red[2][nl2][mo + j] + red[3][nl2][mo + j];
            hv[j] = (f16)(v * LOG2E);
        }
        *(f16x8*)(theta + (size_t)(gbase + nl2) * 32 + mo) = hv;
    }
    __syncthreads();

    // ---- phi ----
#pragma unroll
    for (int m = 0; m < 32; ++m) red[cg][nl][m] = ph[m];
    __syncthreads();
    {
        f16x8 hv;
#pragma unroll
        for (int j = 0; j < 8; ++j) {
            float v = red[0][nl2][mo + j] + red[1][nl2][mo + j]
                    + red[2][nl2][mo + j] + red[3][nl2][mo + j];
            hv[j] = (f16)v;
        }
        *(f16x8*)(phi + (size_t)(gbase + nl2) * 32 + mo) = hv;
    }
    __syncthreads();

    // ---- g (transpose to m-major + per-32-block k-permutation) ----
#pragma unroll
    for (int m = 0; m < 32; ++m) red[cg][nl][m] = gg[m];
    __syncthreads();
    float vsum[8];
#pragma unroll
    for (int j = 0; j < 8; ++j)
        vsum[j] = red[0][nl2][mo + j] + red[1][nl2][mo + j]
                + red[2][nl2][mo + j] + red[3][nl2][mo + j];
    __syncthreads();
    float (*redS)[33] = red[0];
#pragma unroll
    for (int j = 0; j < 8; ++j) redS[nl2][mo + j] = vsum[j];
    __syncthreads();
    {
        int m = t >> 3, n8 = (t & 7) * 8;
        int chunk = n8 >> 5, g5 = (n8 & 31) >> 3;   // dest pos = n8+j
        f16x8 gv;
#pragma unroll
        for (int j = 0; j < 8; ++j) {
            int src = chunk * 32 + (j >> 2) * 16 + g5 * 4 + (j & 3);
            gv[j] = (f16)redS[src][m];
        }
        int bblk = gbase >> 12, nb = gbase & 4095;
        *(f16x8*)(gP + ((size_t)bblk * 32 + m) * 4096 + nb + n8) = gv;
    }
}

// ---------------------------------------------------------------------------
// Kernel 2: flash attention, f16 MFMA, fixed-base softmax (C=12 in the QK
// accumulator init), split-KV x4.  Swapped QK gives S^T with q lane-local;
// thanks to the k-permuted gP, the PV B-operand is formed lane-locally
// (exp2 + cvt_pkrtz only) -- no shuffles, no LDS.  Y^T = gP_frag x P^T.
// ---------------------------------------------------------------------------
__global__ __launch_bounds__(256) void attn_kernel(
    const f16* __restrict__ theta, const f16* __restrict__ phi,
    const f16* __restrict__ gP, f16* __restrict__ ypart,
    float* __restrict__ lpart)
{
    int t = threadIdx.x;
    int wid = t >> 6, lane = t & 63;
    int g = lane >> 4, c15 = lane & 15;
    int b = blockIdx.y, sp = blockIdx.z;
    int qb = blockIdx.x * 64 + wid * 16;

    // theta frag (QK B-operand): B[c][q], q = lane&15, c = g*8+j
    f16x8 a_th = *(const f16x8*)(theta + ((size_t)b * 4096 + qb + c15) * 32 + g * 8);

    f32x4 Y0 = {0.f, 0.f, 0.f, 0.f}, Y1 = {0.f, 0.f, 0.f, 0.f};
    float lsum = 0.f;
    const f32x4 zinit = {-12.f, -12.f, -12.f, -12.f};   // fixed softmax base

    const f16* phiB = phi + (size_t)b * 4096 * 32;
    const f16* gB   = gP  + (size_t)b * 32 * 4096;

    const int ktbeg = sp * 8, ktend = sp * 8 + 8;

    // prologue: phi frags for first kt
    f16x8 bf[8];
#pragma unroll
    for (int t8 = 0; t8 < 8; ++t8)
        bf[t8] = *(const f16x8*)(phiB + (size_t)(ktbeg * 128 + t8 * 16 + c15) * 32 + g * 8);

    for (int kt = ktbeg; kt < ktend; ++kt) {
        int n0 = kt * 128;

        // g A-frags for this kt: issue first so L2 latency hides under QK+exp2
        f16x8 ga0[4], ga1[4];
#pragma unroll
        for (int u = 0; u < 4; ++u) {
            ga0[u] = *(const f16x8*)(gB + (size_t)c15 * 4096 + n0 + u * 32 + g * 8);
            ga1[u] = *(const f16x8*)(gB + (size_t)(16 + c15) * 4096 + n0 + u * 32 + g * 8);
        }

        // QK^T swapped: s[t8][r] = S[k = n0 + t8*16 + g*4 + r][q = c15] - 12
        f32x4 s[8];
#pragma unroll
        for (int t8 = 0; t8 < 8; ++t8)
            s[t8] = __builtin_amdgcn_mfma_f32_16x16x32_f16(bf[t8], a_th, zinit, 0, 0, 0);

        // prefetch phi frags for next kt
        int ktn = (kt + 1 < ktend) ? kt + 1 : kt;
        f16x8 bfn[8];
#pragma unroll
        for (int t8 = 0; t8 < 8; ++t8)
            bfn[t8] = *(const f16x8*)(phiB + (size_t)(ktn * 128 + t8 * 16 + c15) * 32 + g * 8);

        // per 32-k chunk: exp2 + pack (lane-local) then PV MFMA
#pragma unroll
        for (int u = 0; u < 4; ++u) {
            union { unsigned int u4[4]; f16x8 v; } pb;
#pragma unroll
            for (int half = 0; half < 2; ++half) {
                f32x4 sv = s[2 * u + half];
                float p0 = __builtin_amdgcn_exp2f(sv[0]);
                float p1 = __builtin_amdgcn_exp2f(sv[1]);
                float p2 = __builtin_amdgcn_exp2f(sv[2]);
                float p3 = __builtin_amdgcn_exp2f(sv[3]);
                lsum += (p0 + p1) + (p2 + p3);
                union { fp16x2 v; unsigned int u; } cا;
                union { fp16x2 v; unsigned int u; } ca, cb;
                ca.v = __builtin_amdgcn_cvt_pkrtz(p0, p1);
                cb.v = __builtin_amdgcn_cvt_pkrtz(p2, p3);
                pb.u4[half * 2 + 0] = ca.u;
                pb.u4[half * 2 + 1] = cb.u;
            }
            Y0 = __builtin_amdgcn_mfma_f32_16x16x32_f16(ga0[u], pb.v, Y0, 0, 0, 0);
            Y1 = __builtin_amdgcn_mfma_f32_16x16x32_f16(ga1[u], pb.v, Y1, 0, 0, 0);
        }
#pragma unroll
        for (int t8 = 0; t8 < 8; ++t8) bf[t8] = bfn[t8];
    }

    // l: per-lane partial is for q = c15; reduce across the 4 g-groups
    lsum += __shfl_xor(lsum, 16);
    lsum += __shfl_xor(lsum, 32);
    if (g == 0)
        lpart[((size_t)(sp * 8 + b)) * 4096 + qb + c15] = lsum;

    // Y^T: D[m][q]: col(q)=lane&15, row(m)=g*4+r (Y0), +16 (Y1)
    f16* yp = ypart + ((size_t)(sp * 8 + b) * 32) * 4096 + qb;
#pragma unroll
    for (int r = 0; r < 4; ++r) {
        yp[(size_t)(g * 4 + r) * 4096 + c15]      = (f16)Y0[r];
        yp[(size_t)(16 + g * 4 + r) * 4096 + c15] = (f16)Y1[r];
    }
}

// ---------------------------------------------------------------------------
// Kernel 2b: combine split-KV partials: y = sum_s ypart / sum_s lpart
// ---------------------------------------------------------------------------
__global__ __launch_bounds__(256) void combine_kernel(
    const f16* __restrict__ ypart, const float* __restrict__ lpart,
    float* __restrict__ y)
{
    int gid = blockIdx.x * 256 + threadIdx.x;     // 262144 threads, 4 n each
    int n4 = (gid & 1023) * 4;
    int bm = gid >> 10;                           // b*32 + m
    int b = bm >> 5, m = bm & 31;
    float acc0 = 0.f, acc1 = 0.f, acc2 = 0.f, acc3 = 0.f;
    float l0 = 0.f, l1 = 0.f, l2 = 0.f, l3 = 0.f;
#pragma unroll
    for (int s = 0; s < 4; ++s) {
        f16x4 yv = *(const f16x4*)(ypart + ((size_t)(s * 8 + b) * 32 + m) * 4096 + n4);
        float4 lv = *(const float4*)(lpart + ((size_t)(s * 8 + b)) * 4096 + n4);
        acc0 += (float)yv[0]; acc1 += (float)yv[1];
        acc2 += (float)yv[2]; acc3 += (float)yv[3];
        l0 += lv.x; l1 += lv.y; l2 += lv.z; l3 += lv.w;
    }
    float4 o = make_float4(acc0 / l0, acc1 / l1, acc2 / l2, acc3 / l3);
    *(float4*)(y + (size_t)bm * 4096 + n4) = o;
}

// ---------------------------------------------------------------------------
// Kernel 3: bilinear upsample x2 align_corners, f32 in -> f16 out, 2 px/thread
// ---------------------------------------------------------------------------
__global__ __launch_bounds__(256) void upsample_kernel(
    const float* __restrict__ y, f16* __restrict__ yup)
{
    int gid = blockIdx.x * 256 + threadIdx.x;     // 2,097,152 threads
    int xi = gid & 63, Y = (gid >> 6) & 127, bc = gid >> 13;
    const float r = 63.0f / 127.0f;
    float fy = (float)Y * r;
    int y0 = (int)fy; int y1 = min(y0 + 1, 63);
    float wy = fy - (float)y0;
    const float* r0 = y + (size_t)bc * 4096 + y0 * 64;
    const float* r1 = y + (size_t)bc * 4096 + y1 * 64;
    union { unsigned int u; f16 h[2]; } pk;
#pragma unroll
    for (int k = 0; k < 2; ++k) {
        int X = 2 * xi + k;
        float fx = (float)X * r;
        int x0 = (int)fx; int x1 = min(x0 + 1, 63);
        float wx = fx - (float)x0;
        float a  = r0[x0] * (1.f - wy) + r1[x0] * wy;
        float bb = r0[x1] * (1.f - wy) + r1[x1] * wy;
        pk.h[k] = (f16)(a * (1.f - wx) + bb * wx);
    }
    *(unsigned int*)&yup[((size_t)bc * 128 + Y) * 128 + 2 * xi] = pk.u;
}

// ---------------------------------------------------------------------------
// Kernel 4: 3x3 conv as implicit GEMM MFMA. M=64 oc, N=256 px (2 rows x 128),
// K=288 tap-major. Input tile staged once per block (zero-padded halo).
// ---------------------------------------------------------------------------
__global__ __launch_bounds__(256) void conv3x3_kernel(
    const f16* __restrict__ yup, const f16* __restrict__ wT,
    float* __restrict__ out)
{
    __shared__ f16 tile[32 * 4 * 132];            // [c][row 0..3][slot 0..131]
    int tY = blockIdx.x, b = blockIdx.y;
    int t = threadIdx.x;

    // zero halo columns (slots 0,1 and 130,131)
    {
        int u = t & 127, c = u >> 2, rr = u & 3;
        int s0 = c * 528 + rr * 132 + ((t < 128) ? 0 : 130);
        *(unsigned int*)&tile[s0] = 0u;
    }
#pragma unroll
    for (int rd = 0; rd < 8; ++rd) {
        int id = rd * 256 + t;                    // 0..2047
        int c = id >> 6, rr = (id >> 4) & 3, seg = id & 15;
        int iy = 2 * tY - 1 + rr;
        uint4 v = make_uint4(0u, 0u, 0u, 0u);
        if ((unsigned)iy < 128u)
            v = *(const uint4*)(yup + (((size_t)b * 32 + c) * 128 + iy) * 128 + seg * 8);
        int base = c * 528 + rr * 132 + 2 + seg * 8;
        *(unsigned int*)&tile[base + 0] = v.x;
        *(unsigned int*)&tile[base + 2] = v.y;
        *(unsigned int*)&tile[base + 4] = v.z;
        *(unsigned int*)&tile[base + 6] = v.w;
    }
    __syncthreads();

    int wid = t >> 6, lane = t & 63, g = lane >> 4, c15 = lane & 15;
    f32x4 acc[4][4];
#pragma unroll
    for (int mt = 0; mt < 4; ++mt)
#pragma unroll
        for (int nt = 0; nt < 4; ++nt) acc[mt][nt] = (f32x4){0.f, 0.f, 0.f, 0.f};

#pragma unroll
    for (int tap = 0; tap < 9; ++tap) {
        const int dy = tap / 3, dx = tap % 3;     // compile-time
        f16x8 a0 = *(const f16x8*)(wT + (size_t)(c15) * 288 + tap * 32 + g * 8);
        f16x8 a1 = *(const f16x8*)(wT + (size_t)(16 + c15) * 288 + tap * 32 + g * 8);
        f16x8 a2 = *(const f16x8*)(wT + (size_t)(32 + c15) * 288 + tap * 32 + g * 8);
        f16x8 a3 = *(const f16x8*)(wT + (size_t)(48 + c15) * 288 + tap * 32 + g * 8);
#pragma unroll
        for (int nt = 0; nt < 4; ++nt) {
            int ntg = wid * 4 + nt;
            int r_out = ntg >> 3, x0 = (ntg & 7) * 16;
            int base = (g * 8) * 528 + (r_out + dy) * 132 + 1 + x0 + c15 + dx;
            f16x8 bf;
#pragma unroll
            for (int j = 0; j < 8; ++j) bf[j] = tile[base + j * 528];
            acc[0][nt] = __builtin_amdgcn_mfma_f32_16x16x32_f16(a0, bf, acc[0][nt], 0, 0, 0);
            acc[1][nt] = __builtin_amdgcn_mfma_f32_16x16x32_f16(a1, bf, acc[1][nt], 0, 0, 0);
            acc[2][nt] = __builtin_amdgcn_mfma_f32_16x16x32_f16(a2, bf, acc[2][nt], 0, 0, 0);
            acc[3][nt] = __builtin_amdgcn_mfma_f32_16x16x32_f16(a3, bf, acc[3][nt], 0, 0, 0);
        }
    }

#pragma unroll
    for (int mt = 0; mt < 4; ++mt)
#pragma unroll
        for (int nt = 0; nt < 4; ++nt) {
            int ntg = wid * 4 + nt;
            int r_out = ntg >> 3, x0 = (ntg & 7) * 16;
            float* ob = out + ((size_t)b * 128 + 64 + mt * 16 + g * 4) * 16384
                            + (2 * tY + r_out) * 128 + x0 + c15;
#pragma unroll
            for (int r = 0; r < 4; ++r)
                ob[(size_t)r * 16384] = acc[mt][nt][r];
        }
}

// ---------------------------------------------------------------------------
// Kernel 5: copy primary into out channels 0..63 (float4)
// ---------------------------------------------------------------------------
__global__ __launch_bounds__(256) void copy_primary_kernel(
    const float4* __restrict__ p, float4* __restrict__ out)
{
    int gid = blockIdx.x * 256 + threadIdx.x;     // 0..2097151
    const int chunk = (64 * 16384) / 4;           // 262144 float4 per batch
    int b = gid >> 18;
    int off = gid & (chunk - 1);
    out[(size_t)b * 2 * chunk + off] = p[gid];
}

// ---------------------------------------------------------------------------
extern "C" void kernel_launch(void* const* d_in, const int* in_sizes, int n_in,
                              void* d_out, int out_size, void* d_ws, size_t ws_size,
                              hipStream_t stream)
{
    const float* primary = (const float*)d_in[0];
    const float* cross   = (const float*)d_in[1];
    const float* w_theta = (const float*)d_in[2];
    const float* w_phi   = (const float*)d_in[3];
    const float* w_g     = (const float*)d_in[4];
    const float* w_out   = (const float*)d_in[5];
    float* out = (float*)d_out;

    char* wsb = (char*)d_ws;
    f16*   wT    = (f16*)(wsb);                               // 64 KB region
    f16*   theta = (f16*)(wsb + (1u << 16));                  // 2 MB
    f16*   phi   = (f16*)(wsb + (1u << 16) + (2u << 20));     // 2 MB
    f16*   gP    = (f16*)(wsb + (1u << 16) + (4u << 20));     // 2 MB
    float* y     = (float*)(wsb + (1u << 16) + (6u << 20));   // 4 MB
    f16*   yup   = (f16*)(wsb + (1u << 16) + (10u << 20));    // 8 MB
    f16*   ypart = (f16*)(wsb + (1u << 16) + (18u << 20));    // 8 MB
    float* lpart = (float*)(wsb + (1u << 16) + (26u << 20));  // 512 KB

    wconv_kernel<<<72, 256, 0, stream>>>(w_out, wT);
    pool_project_kernel<<<512, 256, 0, stream>>>(primary, cross, w_theta, w_phi, w_g,
                                                 theta, phi, gP);
    attn_kernel<<<dim3(64, 8, 4), 256, 0, stream>>>(theta, phi, gP, ypart, lpart);
    combine_kernel<<<1024, 256, 0, stream>>>(ypart, lpart, y);
    upsample_kernel<<<8192, 256, 0, stream>>>(y, yup);
    conv3x3_kernel<<<dim3(64, 8), 256, 0, stream>>>(yup, wT, out);
    copy_primary_kernel<<<8192, 256, 0, stream>>>((const float4*)primary, (float4*)out);
}